// Round 6
// baseline (1010.480 us; speedup 1.0000x reference)
//
#include <hip/hip_runtime.h>
#include <hip/hip_bf16.h>

// Problem constants
#define NB   8192   // batch
#define NI   2048   // in features
#define NH   2048   // hidden
#define NO   512    // out
#define KP   10240  // 5*2048 augmented K
#define CHNK 4096   // M-chunk rows (fallback path)
#define BNEPS 1e-5f

typedef short bf16x8 __attribute__((ext_vector_type(8)));
typedef float f32x4 __attribute__((ext_vector_type(4)));
typedef unsigned int u32_g __attribute__((address_space(1)));
typedef unsigned int u32_l __attribute__((address_space(3)));

__device__ __forceinline__ void load_lds16(const void* g, void* l) {
  __builtin_amdgcn_global_load_lds((const u32_g*)g, (u32_l*)l, 16, 0, 0);
}

__device__ __forceinline__ unsigned short f2bf(float f) {
  __hip_bfloat16 h = __float2bfloat16(f);
  unsigned short u;
  __builtin_memcpy(&u, &h, 2);
  return u;
}

// ---------------------------------------------------------------------------
// Build W'[o][k'] with k' = s*Kin + i; s=0: wbase[o][i]; s=1..4: coef[i][o][s]*scaler[o].
// Also acc[o] += sum_i coef[i][o][0]  (T0 == 1 folds into bias).
// ---------------------------------------------------------------------------
__global__ __launch_bounds__(256) void build_w_kernel(
    const float* __restrict__ wbase, const float* __restrict__ coef,
    const float* __restrict__ scaler, __hip_bfloat16* __restrict__ Wp,
    float* __restrict__ acc, int Nout, int Kin)
{
  __shared__ float lds0[64][65];
  __shared__ __hip_bfloat16 ldsT[64][4][68];
  const int t = threadIdx.x;
  const int o0 = blockIdx.x * 64;
  const int i0 = blockIdx.y * 64;

  for (int r = t; r < 64 * 64 * 5; r += 256) {
    int li = r / 320;
    int rem = r - li * 320;
    int lo = rem / 5;
    int d = rem - lo * 5;
    float v = coef[((size_t)(i0 + li) * Nout + (o0 + lo)) * 5 + d];
    if (d == 0) lds0[lo][li] = v;
    else        ldsT[lo][d - 1][li] = __float2bfloat16(v);
  }
  __syncthreads();

  const size_t Kw = (size_t)5 * Kin;
  for (int r = t; r < 64 * 4 * 64; r += 256) {
    int li = r & 63;
    int d  = (r >> 6) & 3;
    int lo = r >> 8;
    float v = __bfloat162float(ldsT[lo][d][li]) * scaler[o0 + lo];
    Wp[(size_t)(o0 + lo) * Kw + (size_t)(d + 1) * Kin + i0 + li] = __float2bfloat16(v);
  }
  for (int r = t; r < 64 * 64; r += 256) {
    int li = r & 63;
    int lo = r >> 6;
    Wp[(size_t)(o0 + lo) * Kw + i0 + li] =
        __float2bfloat16(wbase[(size_t)(o0 + lo) * Kin + i0 + li]);
  }
  {
    int lo = t >> 2, q = t & 3;
    float s = 0.f;
    #pragma unroll
    for (int j = 0; j < 16; ++j) s += lds0[lo][q * 16 + j];
    s += __shfl_xor(s, 1);
    s += __shfl_xor(s, 2);
    if (q == 0) atomicAdd(&acc[o0 + lo], s);
  }
}

// ---------------------------------------------------------------------------
// A1'[b][k']: slot0 = x, slots1..4 = T_d(tanh(x)).
// ---------------------------------------------------------------------------
__global__ __launch_bounds__(256) void build_a1_kernel(
    const float* __restrict__ x, __hip_bfloat16* __restrict__ Ap, int b0)
{
  const size_t idx = ((size_t)blockIdx.x * 256 + threadIdx.x) * 4;
  const size_t row = idx >> 11;
  const int i = (int)(idx & 2047);
  const float4 xv = *(const float4*)(x + (size_t)b0 * NI + idx);
  const float xa[4] = {xv.x, xv.y, xv.z, xv.w};
  unsigned short u0[4], u1[4], u2[4], u3[4], u4[4];
  #pragma unroll
  for (int j = 0; j < 4; ++j) {
    float v  = xa[j];
    float tn = tanhf(v);
    float t2 = fmaf(2.f * tn, tn, -1.f);
    float t3 = fmaf(2.f * tn, t2, -tn);
    float t4 = fmaf(2.f * tn, t3, -t2);
    u0[j] = f2bf(v);  u1[j] = f2bf(tn); u2[j] = f2bf(t2);
    u3[j] = f2bf(t3); u4[j] = f2bf(t4);
  }
  __hip_bfloat16* bp = Ap + row * KP + i;
  *(ushort4*)(bp)          = make_ushort4(u0[0], u0[1], u0[2], u0[3]);
  *(ushort4*)(bp + NI)     = make_ushort4(u1[0], u1[1], u1[2], u1[3]);
  *(ushort4*)(bp + 2 * NI) = make_ushort4(u2[0], u2[1], u2[2], u2[3]);
  *(ushort4*)(bp + 3 * NI) = make_ushort4(u3[0], u3[1], u3[2], u3[3]);
  *(ushort4*)(bp + 4 * NI) = make_ushort4(u4[0], u4[1], u4[2], u4[3]);
}

// ---------------------------------------------------------------------------
// A2': hn = gamma*(h-mu)*rsig + beta; slot0 = hn; slots1..4 = T_d(tanh(hn)).
// ---------------------------------------------------------------------------
__global__ __launch_bounds__(256) void build_a2_kernel(
    const __hip_bfloat16* __restrict__ h, const float* __restrict__ mu,
    const float* __restrict__ rsig, const float* __restrict__ gam,
    const float* __restrict__ bet, __hip_bfloat16* __restrict__ Ap, int b0)
{
  const size_t idx = ((size_t)blockIdx.x * 256 + threadIdx.x) * 4;
  const size_t row = idx >> 11;
  const int j0 = (int)(idx & 2047);
  const ushort4 hv = *(const ushort4*)(h + (size_t)b0 * NH + idx);
  const float4 muv = *(const float4*)(mu + j0);
  const float4 rsv = *(const float4*)(rsig + j0);
  const float4 gv  = *(const float4*)(gam + j0);
  const float4 bv  = *(const float4*)(bet + j0);
  unsigned short hu[4] = {hv.x, hv.y, hv.z, hv.w};
  const float ma[4] = {muv.x, muv.y, muv.z, muv.w};
  const float ra[4] = {rsv.x, rsv.y, rsv.z, rsv.w};
  const float ga[4] = {gv.x, gv.y, gv.z, gv.w};
  const float ba[4] = {bv.x, bv.y, bv.z, bv.w};
  unsigned short u0[4], u1[4], u2[4], u3[4], u4[4];
  #pragma unroll
  for (int j = 0; j < 4; ++j) {
    __hip_bfloat16 hb;
    __builtin_memcpy(&hb, &hu[j], 2);
    float hv_f = __bfloat162float(hb);
    float hn = fmaf(ga[j] * (hv_f - ma[j]), ra[j], ba[j]);
    float tn = tanhf(hn);
    float t2 = fmaf(2.f * tn, tn, -1.f);
    float t3 = fmaf(2.f * tn, t2, -tn);
    float t4 = fmaf(2.f * tn, t3, -t2);
    u0[j] = f2bf(hn); u1[j] = f2bf(tn); u2[j] = f2bf(t2);
    u3[j] = f2bf(t3); u4[j] = f2bf(t4);
  }
  __hip_bfloat16* bp = Ap + row * KP + j0;
  *(ushort4*)(bp)          = make_ushort4(u0[0], u0[1], u0[2], u0[3]);
  *(ushort4*)(bp + NH)     = make_ushort4(u1[0], u1[1], u1[2], u1[3]);
  *(ushort4*)(bp + 2 * NH) = make_ushort4(u2[0], u2[1], u2[2], u2[3]);
  *(ushort4*)(bp + 3 * NH) = make_ushort4(u3[0], u3[1], u3[2], u3[3]);
  *(ushort4*)(bp + 4 * NH) = make_ushort4(u4[0], u4[1], u4[2], u4[3]);
}

// ---------------------------------------------------------------------------
// BatchNorm stats over bf16 h.
// ---------------------------------------------------------------------------
__global__ __launch_bounds__(256) void bn_stats_kernel(
    const __hip_bfloat16* __restrict__ h, float* __restrict__ psum,
    float* __restrict__ psq)
{
  const int col = blockIdx.x * 256 + threadIdx.x;
  const int r0 = blockIdx.y * 256;
  float s = 0.f, q = 0.f;
  for (int r = 0; r < 256; ++r) {
    float v = __bfloat162float(h[(size_t)(r0 + r) * NH + col]);
    s += v;
    q = fmaf(v, v, q);
  }
  psum[(size_t)blockIdx.y * NH + col] = s;
  psq [(size_t)blockIdx.y * NH + col] = q;
}

__global__ __launch_bounds__(256) void bn_finalize_kernel(
    const float* __restrict__ psum, const float* __restrict__ psq,
    float* __restrict__ mu, float* __restrict__ rsig)
{
  const int j = blockIdx.x * 256 + threadIdx.x;
  float s = 0.f, q = 0.f;
  for (int c = 0; c < 32; ++c) {
    s += psum[(size_t)c * NH + j];
    q += psq [(size_t)c * NH + j];
  }
  const float invB = 1.f / (float)NB;
  float m = s * invB;
  float var = fmaf(q, invB, -m * m);
  mu[j] = m;
  rsig[j] = rsqrtf(var + BNEPS);
}

// ---------------------------------------------------------------------------
// out[idx] = p0[idx] + p1[idx] + (b2[col] + s2[col]*acc2[col])   (split-K=2)
// ---------------------------------------------------------------------------
__global__ __launch_bounds__(256) void reduce2_kernel(
    const float* __restrict__ p, float* __restrict__ out,
    const float* __restrict__ bb, const float* __restrict__ bs,
    const float* __restrict__ bacc, int rows)
{
  const size_t idx = ((size_t)blockIdx.x * 256 + threadIdx.x) * 4;
  const int col = (int)(idx & (NO - 1));
  const float4 a = *(const float4*)(p + idx);
  const float4 b = *(const float4*)(p + (size_t)rows * NO + idx);
  const float4 bbv = *(const float4*)(bb + col);
  const float4 bsv = *(const float4*)(bs + col);
  const float4 bav = *(const float4*)(bacc + col);
  float4 o;
  o.x = a.x + b.x + bbv.x + bsv.x * bav.x;
  o.y = a.y + b.y + bbv.y + bsv.y * bav.y;
  o.z = a.z + b.z + bbv.z + bsv.z * bav.z;
  o.w = a.w + b.w + bbv.w + bsv.w * bav.w;
  *(float4*)(out + idx) = o;
}

// ---------------------------------------------------------------------------
// GEMM1: 256x256 tile, BK=64, 8 waves (2x4), per-wave 128x64, LDS 128 KiB
// double-buffered. Per K-tile: {12 ds_read + MFMA kk0} -> lgkm(0)+barrier ->
// stage next tile into freed buffer (8 gloads) -> MFMA kk1 -> counted
// vmcnt(8)+barrier.  T2 swizzle: pre-swizzled global source + XOR'd ds_read.
// C bf16 = acc + bias(n).
// ---------------------------------------------------------------------------
__global__ __launch_bounds__(512, 1) void gemm_8w(
    const __hip_bfloat16* __restrict__ A, const __hip_bfloat16* __restrict__ Bm,
    __hip_bfloat16* __restrict__ C, const float* __restrict__ bb,
    const float* __restrict__ bs, const float* __restrict__ bacc,
    int N, int K, int nit)   // nit = K/128 (2 K-tiles per iteration)
{
  __shared__ __attribute__((aligned(16))) __hip_bfloat16 As[2][256][64];
  __shared__ __attribute__((aligned(16))) __hip_bfloat16 Bs[2][256][64];
  const int tid  = threadIdx.x;
  const int lane = tid & 63;
  const int w    = tid >> 6;
  const int swz = ((int)blockIdx.x & 7) * ((int)gridDim.x >> 3) + ((int)blockIdx.x >> 3);
  const int nTN = N >> 8;
  const int m0 = (swz / nTN) * 256;
  const int n0 = (swz % nTN) * 256;
  const int wrow = (w >> 2) * 128;   // wave output rows: wrow..wrow+127
  const int wcol = (w & 3) * 64;     // wave output cols: wcol..wcol+63

  // staging: wave w covers granules {w, w+8, w+16, w+24} (8 rows each);
  // lane l -> row +(l>>3), 16B at swizzled col (involution with read-side XOR)
  const int srow = lane >> 3;
  const int scol = ((lane & 7) ^ srow) * 8;
  const __hip_bfloat16* Ag = A  + (size_t)(m0 + w * 8 + srow) * K + scol;
  const __hip_bfloat16* Bg = Bm + (size_t)(n0 + w * 8 + srow) * K + scol;

  f32x4 acc[8][4];
  #pragma unroll
  for (int m = 0; m < 8; ++m)
    #pragma unroll
    for (int n = 0; n < 4; ++n) {
      f32x4 z = {0.f, 0.f, 0.f, 0.f};
      acc[m][n] = z;
    }

  const int fr = lane & 15;
  const int kg = (lane >> 4) * 8;
  const int swz_r = (fr & 7) * 8;

  #define STAGE8(buf, kt)                                                      \
    do {                                                                       \
      _Pragma("unroll")                                                        \
      for (int c = 0; c < 4; ++c)                                              \
        load_lds16(Ag + (size_t)(c * 64) * K + (kt), &As[buf][w * 8 + c * 64][0]); \
      _Pragma("unroll")                                                        \
      for (int c = 0; c < 4; ++c)                                              \
        load_lds16(Bg + (size_t)(c * 64) * K + (kt), &Bs[buf][w * 8 + c * 64][0]); \
    } while (0)

  // One K-tile from buffer BUF; optionally stage tile (ktS) into same buffer
  // after all reads retired; counted vmcnt keeps the other buffer's stage in
  // flight only.
  #define KTILE(BUF, DOSTAGE, KTS)                                             \
    do {                                                                       \
      _Pragma("unroll")                                                        \
      for (int kk = 0; kk < 2; ++kk) {                                         \
        bf16x8 bfr[4], af[8];                                                  \
        _Pragma("unroll")                                                      \
        for (int n = 0; n < 4; ++n)                                            \
          bfr[n] = *(const bf16x8*)&Bs[BUF][wcol + n * 16 + fr][(kk * 32 + kg) ^ swz_r]; \
        _Pragma("unroll")                                                      \
        for (int m = 0; m < 8; ++m)                                            \
          af[m] = *(const bf16x8*)&As[BUF][wrow + m * 16 + fr][(kk * 32 + kg) ^ swz_r]; \
        if (kk == 1) {                                                         \
          asm volatile("s_waitcnt lgkmcnt(0)" ::: "memory");                   \
          __builtin_amdgcn_s_barrier();                                        \
          if (DOSTAGE) STAGE8(BUF, KTS);                                       \
        }                                                                      \
        __builtin_amdgcn_s_setprio(1);                                         \
        _Pragma("unroll")                                                      \
        for (int m = 0; m < 8; ++m)                                            \
          _Pragma("unroll")                                                    \
          for (int n = 0; n < 4; ++n)                                          \
            acc[m][n] = __builtin_amdgcn_mfma_f32_16x16x32_bf16(               \
                af[m], bfr[n], acc[m][n], 0, 0, 0);                            \
        __builtin_amdgcn_s_setprio(0);                                         \
      }                                                                        \
      if (DOSTAGE) asm volatile("s_waitcnt vmcnt(8)" ::: "memory");            \
      else         asm volatile("s_waitcnt vmcnt(0)" ::: "memory");            \
      __builtin_amdgcn_s_barrier();                                            \
    } while (0)

  // Prologue: stage tiles 0 and 1; wait for tile 0 only (counted).
  STAGE8(0, 0);
  STAGE8(1, 64);
  asm volatile("s_waitcnt vmcnt(8)" ::: "memory");
  __builtin_amdgcn_s_barrier();

  for (int i = 0; i < nit; ++i) {
    const int kts = (2 * i + 2) * 64;
    const bool ds = (i + 1 < nit);
    KTILE(0, ds, kts);
    KTILE(1, ds, kts + 64);
  }
  #undef KTILE
  #undef STAGE8

  const int cr = (lane >> 4) * 4;
  const int cc = lane & 15;
  #pragma unroll
  for (int n = 0; n < 4; ++n) {
    const int col = n0 + wcol + n * 16 + cc;
    const float bias = bb[col] + bs[col] * bacc[col];
    #pragma unroll
    for (int m = 0; m < 8; ++m) {
      __hip_bfloat16* Cp = C + (size_t)(m0 + wrow + m * 16 + cr) * N + col;
      #pragma unroll
      for (int r = 0; r < 4; ++r)
        Cp[(size_t)r * N] = __float2bfloat16(acc[m][n][r] + bias);
    }
  }
}

// ---------------------------------------------------------------------------
// GEMM2: split-K partials (NO atomics). 128x128 tile, 4 waves, double-buffered
// counted-vmcnt loop (proven R4 structure). Partial f32 written to
// P + split*M*N.  Grid = nsplit * bps (bps = 1<<lg2bps).
// ---------------------------------------------------------------------------
__global__ __launch_bounds__(256, 2) void gemm_sp(
    const __hip_bfloat16* __restrict__ A, const __hip_bfloat16* __restrict__ Bm,
    float* __restrict__ P, int M, int N, int K, int nt, int lg2bps)
{
  __shared__ __attribute__((aligned(16))) __hip_bfloat16 As[2][128][64];
  __shared__ __attribute__((aligned(16))) __hip_bfloat16 Bs[2][128][64];
  const int tid  = threadIdx.x;
  const int lane = tid & 63;
  const int w    = tid >> 6;
  int swz = ((int)blockIdx.x & 7) * ((int)gridDim.x >> 3) + ((int)blockIdx.x >> 3);
  const int split = swz >> lg2bps;
  swz &= (1 << lg2bps) - 1;
  const int k0 = split * (nt * 64);
  const int nTN = N >> 7;
  const int m0 = (swz / nTN) * 128;
  const int n0 = (swz % nTN) * 128;
  const int wr = (w >> 1) * 64;
  const int wc = (w & 1) * 64;

  const int srow = lane >> 3;
  const int scol = (((lane & 7) ^ srow) * 8);
  const __hip_bfloat16* Ag = A  + (size_t)(m0 + w * 32 + srow) * K + k0 + scol;
  const __hip_bfloat16* Bg = Bm + (size_t)(n0 + w * 32 + srow) * K + k0 + scol;

  f32x4 acc[4][4];
  #pragma unroll
  for (int m = 0; m < 4; ++m)
    #pragma unroll
    for (int n = 0; n < 4; ++n) {
      f32x4 z = {0.f, 0.f, 0.f, 0.f};
      acc[m][n] = z;
    }

  const int fr = lane & 15;
  const int kg = (lane >> 4) * 8;
  const int swz_r = (fr & 7) * 8;

  #define STAGE(buf, kt)                                                     \
    do {                                                                     \
      _Pragma("unroll")                                                      \
      for (int c = 0; c < 4; ++c)                                            \
        load_lds16(Ag + (size_t)c * 8 * K + (kt), &As[buf][w * 32 + c * 8][0]); \
      _Pragma("unroll")                                                      \
      for (int c = 0; c < 4; ++c)                                            \
        load_lds16(Bg + (size_t)c * 8 * K + (kt), &Bs[buf][w * 32 + c * 8][0]); \
    } while (0)

  STAGE(0, 0);
  STAGE(1, 64);
  asm volatile("s_waitcnt vmcnt(8)" ::: "memory");
  __builtin_amdgcn_s_barrier();

  for (int it = 0; it < nt; ++it) {
    const int cur = it & 1;
    bf16x8 af[4][2], bfr[4][2];
    #pragma unroll
    for (int m = 0; m < 4; ++m)
      #pragma unroll
      for (int kk = 0; kk < 2; ++kk)
        af[m][kk] = *(const bf16x8*)&As[cur][wr + m * 16 + fr][(kk * 32 + kg) ^ swz_r];
    #pragma unroll
    for (int n = 0; n < 4; ++n)
      #pragma unroll
      for (int kk = 0; kk < 2; ++kk)
        bfr[n][kk] = *(const bf16x8*)&Bs[cur][wc + n * 16 + fr][(kk * 32 + kg) ^ swz_r];
    asm volatile("s_waitcnt lgkmcnt(0)" ::: "memory");
    __builtin_amdgcn_s_barrier();
    const bool pre = (it + 2 < nt);
    if (pre) STAGE(cur, (it + 2) * 64);
    __builtin_amdgcn_s_setprio(1);
    #pragma unroll
    for (int m = 0; m < 4; ++m)
      #pragma unroll
      for (int n = 0; n < 4; ++n)
        #pragma unroll
        for (int kk = 0; kk < 2; ++kk)
          acc[m][n] = __builtin_amdgcn_mfma_f32_16x16x32_bf16(
              af[m][kk], bfr[n][kk], acc[m][n], 0, 0, 0);
    __builtin_amdgcn_s_setprio(0);
    if (pre) asm volatile("s_waitcnt vmcnt(8)" ::: "memory");
    else     asm volatile("s_waitcnt vmcnt(0)" ::: "memory");
    __builtin_amdgcn_s_barrier();
  }
  #undef STAGE

  const int cr = (lane >> 4) * 4;
  const int cc = lane & 15;
  float* Pb = P + (size_t)split * M * N;
  #pragma unroll
  for (int n = 0; n < 4; ++n) {
    const int col = n0 + wc + n * 16 + cc;
    #pragma unroll
    for (int m = 0; m < 4; ++m) {
      float* Pp = Pb + (size_t)(m0 + wr + m * 16 + cr) * N + col;
      #pragma unroll
      for (int r = 0; r < 4; ++r)
        Pp[(size_t)r * N] = acc[m][n][r];
    }
  }
}

// ---------------------------------------------------------------------------
extern "C" void kernel_launch(void* const* d_in, const int* in_sizes, int n_in,
                              void* d_out, int out_size, void* d_ws, size_t ws_size,
                              hipStream_t stream) {
  (void)in_sizes; (void)n_in; (void)out_size;
  const float* x   = (const float*)d_in[0];
  const float* w1  = (const float*)d_in[1];
  const float* b1  = (const float*)d_in[2];
  const float* c1  = (const float*)d_in[3];
  const float* s1  = (const float*)d_in[4];
  const float* gam = (const float*)d_in[5];
  const float* bet = (const float*)d_in[6];
  const float* w2  = (const float*)d_in[7];
  const float* b2  = (const float*)d_in[8];
  const float* c2  = (const float*)d_in[9];
  const float* s2  = (const float*)d_in[10];
  float* out = (float*)d_out;

  const bool full = ws_size >= 243820544ULL;
  const size_t apBytes = full ? 167772160ULL : 83886080ULL;
  char* ws = (char*)d_ws;
  __hip_bfloat16* Ap = (__hip_bfloat16*)ws;
  __hip_bfloat16* Wp = (__hip_bfloat16*)(ws + apBytes);
  __hip_bfloat16* hb = (__hip_bfloat16*)(ws + apBytes + 41943040ULL);
  float* pbuf = (float*)hb;   // hb is dead after build_a2; reused for GEMM2 partials
  char* tail = ws + apBytes + 41943040ULL + 33554432ULL;
  float* acc1 = (float*)(tail);
  float* acc2 = (float*)(tail + 8192);
  float* psum = (float*)(tail + 10240);
  float* psq  = (float*)(tail + 272384);
  float* mu   = (float*)(tail + 534528);
  float* rsig = (float*)(tail + 542720);

  dim3 blk(256);
  dim3 blk512(512);
  hipMemsetAsync(acc1, 0, 8192 + 2048, stream);

  // Layer 1 weights + bias-acc
  build_w_kernel<<<dim3(NH / 64, NI / 64), blk, 0, stream>>>(w1, c1, s1, Wp, acc1, NH, NI);

  if (full) {
    build_a1_kernel<<<(NB * NI / 4) / 256, blk, 0, stream>>>(x, Ap, 0);
    gemm_8w<<<(NB / 256) * (NH / 256), blk512, 0, stream>>>(
        Ap, Wp, hb, b1, s1, acc1, NH, KP, KP / 128);
  } else {
    for (int ch = 0; ch < 2; ++ch) {
      int b0 = ch * CHNK;
      build_a1_kernel<<<(CHNK * NI / 4) / 256, blk, 0, stream>>>(x, Ap, b0);
      gemm_8w<<<(CHNK / 256) * (NH / 256), blk512, 0, stream>>>(
          Ap, Wp, hb + (size_t)b0 * NH, b1, s1, acc1, NH, KP, KP / 128);
    }
  }

  // BatchNorm statistics
  bn_stats_kernel<<<dim3(NH / 256, 32), blk, 0, stream>>>(hb, psum, psq);
  bn_finalize_kernel<<<NH / 256, blk, 0, stream>>>(psum, psq, mu, rsig);

  // Layer 2 weights + bias-acc (Wp reused)
  build_w_kernel<<<dim3(NO / 64, NH / 64), blk, 0, stream>>>(w2, c2, s2, Wp, acc2, NO, NH);

  if (full) {
    build_a2_kernel<<<(NB * NH / 4) / 256, blk, 0, stream>>>(hb, mu, rsig, gam, bet, Ap, 0);
    // split-K=2 partials into pbuf (hb region, now dead): 2 x 256 = 512 blocks
    gemm_sp<<<2 * (NB / 128) * (NO / 128), blk, 0, stream>>>(
        Ap, Wp, pbuf, NB, NO, KP, (KP / 2) / 64, 8);
    reduce2_kernel<<<(NB * NO / 4) / 256, blk, 0, stream>>>(
        pbuf, out, b2, s2, acc2, NB);
  } else {
    for (int ch = 0; ch < 2; ++ch) {
      int b0 = ch * CHNK;
      build_a2_kernel<<<(CHNK * NH / 4) / 256, blk, 0, stream>>>(hb, mu, rsig, gam, bet, Ap, b0);
      gemm_sp<<<2 * (CHNK / 128) * (NO / 128), blk, 0, stream>>>(
          Ap, Wp, pbuf, CHNK, NO, KP, (KP / 2) / 64, 7);
      reduce2_kernel<<<(CHNK * NO / 4) / 256, blk, 0, stream>>>(
          pbuf, out + (size_t)b0 * NO, b2, s2, acc2, CHNK);
    }
  }
}